// Round 16
// baseline (332.995 us; speedup 1.0000x reference)
//
#include <hip/hip_runtime.h>
#include <math.h>

#define NLEV 16
#define RES  64
#define NBIN 4096     // 64x64 Morton bins
#define SRTBLK 512    // sort mega-blocks (2 blocks/CU at 1024 threads)

typedef _Float16 f16;
typedef f16 f16x8 __attribute__((ext_vector_type(8)));
typedef float f32x4 __attribute__((ext_vector_type(4)));

struct LevelMeta {
    float scale[NLEV];
    int   r1[NLEV];    // grid row stride = r+1
    int   off[NLEV];   // element offset into embeddings table
};

struct alignas(8) F4 { float x, y, z, w; };

__device__ inline unsigned spread2d(unsigned v) {
    v = (v | (v << 4)) & 0x0F0Fu;
    v = (v | (v << 2)) & 0x3333u;
    v = (v | (v << 1)) & 0x5555u;
    return v;
}

__device__ inline unsigned bin_of(float x0, float x1) {
    int bx = (int)(x0 * (float)RES); bx = bx < 0 ? 0 : (bx > RES - 1 ? RES - 1 : bx);
    int by = (int)(x1 * (float)RES); by = by < 0 ? 0 : (by > RES - 1 ? RES - 1 : by);
    return spread2d((unsigned)bx) | (spread2d((unsigned)by) << 1);  // [0, NBIN)
}

// ---- K1: per-mega-block LDS histogram -> hist2d[bin][block] (no global atomics) ----
__global__ __launch_bounds__(1024)
void hist_kernel(const float* __restrict__ x, const float* __restrict__ cmax,
                 unsigned* __restrict__ hist2d, int ppb) {
    __shared__ unsigned lh[NBIN];
    const int t = threadIdx.x, bid = blockIdx.x;
    for (int i = t; i < NBIN; i += 1024) lh[i] = 0;
    __syncthreads();
    const float c0 = cmax[1], c1 = cmax[0];
    const int base = bid * ppb;
    for (int i = t; i < ppb; i += 1024) {
        float2 xy = ((const float2*)x)[base + i];
        atomicAdd(&lh[bin_of(xy.x / c0, xy.y / c1)], 1u);   // LDS atomic
    }
    __syncthreads();
    for (int i = t; i < NBIN; i += 1024)
        hist2d[i * SRTBLK + bid] = lh[i];                   // coalesced per wave
}

// ---- K2a: one wave per bin — in-place exclusive scan over SRTBLK blocks + bin total ----
// row = SRTBLK entries = SRTBLK/4 uint4; processed in 64-uint4 passes with carry.
__global__ __launch_bounds__(256)
void scanbin_kernel(unsigned* __restrict__ hist2d, unsigned* __restrict__ binTot) {
    const int wave = threadIdx.x >> 6, lane = threadIdx.x & 63;
    const int bin = blockIdx.x * 4 + wave;
    uint4* row = (uint4*)(hist2d + (size_t)bin * SRTBLK);
    unsigned carry = 0;
#pragma unroll
    for (int half = 0; half < SRTBLK / 256; ++half) {
        uint4 v = row[half * 64 + lane];
        unsigned s = v.x + v.y + v.z + v.w;
        unsigned xs = s;
#pragma unroll
        for (int o = 1; o < 64; o <<= 1) {
            unsigned y = (unsigned)__shfl_up((int)xs, o);
            if (lane >= o) xs += y;
        }
        unsigned ex = carry + xs - s;   // exclusive base for this lane's 4 entries
        uint4 w;
        w.x = ex;
        w.y = w.x + v.x;
        w.z = w.y + v.y;
        w.w = w.z + v.z;
        row[half * 64 + lane] = w;      // hist2d becomes pre2d
        carry += (unsigned)__shfl((int)xs, 63);  // this pass's total
    }
    if (lane == 0) binTot[bin] = carry;
}

// ---- K2b: exclusive scan of 4096 bin totals (one block, 16/thread) ----
__global__ __launch_bounds__(256)
void scantot_kernel(const unsigned* __restrict__ tot, unsigned* __restrict__ basev) {
    __shared__ unsigned wsum[4];
    int t = threadIdx.x;
    unsigned v[16];
    unsigned s = 0;
#pragma unroll
    for (int k = 0; k < 4; ++k) {
        uint4 h = ((const uint4*)tot)[t * 4 + k];
        v[4 * k] = h.x; v[4 * k + 1] = h.y; v[4 * k + 2] = h.z; v[4 * k + 3] = h.w;
        s += h.x + h.y + h.z + h.w;
    }
    int lane = t & 63, w = t >> 6;
    unsigned xs = s;
#pragma unroll
    for (int o = 1; o < 64; o <<= 1) {
        unsigned y = (unsigned)__shfl_up((int)xs, o);
        if (lane >= o) xs += y;
    }
    if (lane == 63) wsum[w] = xs;
    __syncthreads();
    unsigned wo = 0;
    for (int k = 0; k < w; ++k) wo += wsum[k];
    unsigned run = wo + xs - s;
#pragma unroll
    for (int j = 0; j < 16; ++j) {
        basev[t * 16 + j] = run;
        run += v[j];
    }
}

// ---- K3: scatter — rank = binBase[b] + pre2d[b][bid] + LDS-local seq ----
__global__ __launch_bounds__(1024)
void scatter_kernel(const float* __restrict__ x, const float* __restrict__ cmax,
                    const unsigned* __restrict__ pre2d,
                    const unsigned* __restrict__ binBase,
                    unsigned* __restrict__ pidx, float2* __restrict__ px, int ppb) {
    __shared__ unsigned lseq[NBIN];
    const int t = threadIdx.x, bid = blockIdx.x;
    for (int i = t; i < NBIN; i += 1024) lseq[i] = 0;
    __syncthreads();
    const float c0 = cmax[1], c1 = cmax[0];
    const int base = bid * ppb;
    for (int i = t; i < ppb; i += 1024) {
        int p = base + i;
        float2 xy = ((const float2*)x)[p];
        float x0 = xy.x / c0, x1 = xy.y / c1;
        unsigned b = bin_of(x0, x1);
        unsigned s = atomicAdd(&lseq[b], 1u);   // LDS atomic
        unsigned rank = binBase[b] + pre2d[(size_t)b * SRTBLK + bid] + s;
        pidx[rank] = (unsigned)p;
        float2 v; v.x = x0; v.y = x1;
        px[rank] = v;
    }
}

// ---- fused hashgrid + MLP (proven body, LDS weights, 3 WG/CU) ----
// LDS: w0s 5120B + w1s 9216B + w2s 2304B + wbuf 36864B = 53504B -> 3 WG/CU
__global__ __launch_bounds__(256, 3)
void hashmlp_kernel(const float* __restrict__ x,
                    const float* __restrict__ cmax,
                    const unsigned* __restrict__ pidx,   // may be null (fallback)
                    const float2* __restrict__ px,       // may be null
                    const float* __restrict__ emb,
                    const float* __restrict__ w0,
                    const float* __restrict__ b0,
                    const float* __restrict__ w1,
                    const float* __restrict__ b1,
                    const float* __restrict__ w2,
                    const float* __restrict__ b2,
                    float* __restrict__ out,
                    int npts, int nblk,
                    LevelMeta meta)
{
    __shared__ f16 w0s[64 * 40];
    __shared__ f16 w1s[64 * 72];
    __shared__ f16 w2s[16 * 72];
    __shared__ f16 wbuf[4][4608];

    const int tid  = threadIdx.x;
    const int lane = tid & 63;
    const int wave = tid >> 6;

    // phase 1: weight loads into registers (stores deferred past gather)
    float w0t[8], w1t[16], w2t[4];
#pragma unroll
    for (int k = 0; k < 8; ++k)  w0t[k] = w0[tid + 256 * k];
#pragma unroll
    for (int k = 0; k < 16; ++k) w1t[k] = w1[tid + 256 * k];
#pragma unroll
    for (int k = 0; k < 4; ++k) {
        int i = tid + 256 * k; int r = i >> 6, c = i & 63;
        w2t[k] = (r < 3) ? w2[r * 64 + c] : 0.f;
    }

    // XCD-chunked swizzle: contiguous sorted (spatial) range per XCD
    int bid = blockIdx.x;
    int cpx = nblk >> 3;
    int swz = (bid & 7) * cpx + (bid >> 3);
    const int g = swz * 256 + tid;
    const int gblk = swz * 256 + wave * 64;

    int p;
    float x0, x1;
    if (pidx) {
        p = (int)pidx[g];
        float2 xy = px[g];
        x0 = xy.x; x1 = xy.y;
    } else {
        p = g;
        float2 xy = ((const float2*)x)[p];
        x0 = xy.x / cmax[1];
        x1 = xy.y / cmax[0];
    }

    // phase 2: gather (compiler-scheduled)
    float fr[32];
#pragma unroll
    for (int l = 0; l < NLEV; ++l) {
        const float sc = meta.scale[l];
        const int r1 = meta.r1[l];
        const int off = meta.off[l];
        float p0 = x0 * sc + 0.5f;
        float p1 = x1 * sc + 0.5f;
        float g0 = floorf(p0), g1 = floorf(p1);
        float f0 = p0 - g0, f1 = p1 - g1;
        int i0 = (int)g0, i1 = (int)g1;
        const float* ebf = emb + 2 * (off + i1 * r1 + i0);
        F4 lo = *(const F4*)ebf;              // e00.x e00.y e10.x e10.y
        F4 hi = *(const F4*)(ebf + 2 * r1);   // e01.x e01.y e11.x e11.y
        float omf0 = 1.f - f0, omf1 = 1.f - f1;
        float w00 = omf0 * omf1, w01 = omf0 * f1, w10 = f0 * omf1, w11 = f0 * f1;
        float a0 = w00 * lo.x; a0 += w01 * hi.x; a0 += w10 * lo.z; a0 += w11 * hi.z;
        float a1 = w00 * lo.y; a1 += w01 * hi.y; a1 += w10 * lo.w; a1 += w11 * hi.w;
        fr[2 * l]     = a0;
        fr[2 * l + 1] = a1;
    }

    // phase 3: weight stores to LDS
#pragma unroll
    for (int k = 0; k < 8; ++k)  { int i = tid + 256 * k; w0s[(i >> 5) * 40 + (i & 31)] = (f16)w0t[k]; }
#pragma unroll
    for (int k = 0; k < 16; ++k) { int i = tid + 256 * k; w1s[(i >> 6) * 72 + (i & 63)] = (f16)w1t[k]; }
#pragma unroll
    for (int k = 0; k < 4; ++k)  { int i = tid + 256 * k; w2s[(i >> 6) * 72 + (i & 63)] = (f16)w2t[k]; }

    // out_lc0 (fp32, exact) at original position
    float* outlc = out + (size_t)npts * 3 + (size_t)p * 32;
#pragma unroll
    for (int c = 0; c < 8; ++c) {
        float4 v;
        v.x = fr[4 * c]; v.y = fr[4 * c + 1]; v.z = fr[4 * c + 2]; v.w = fr[4 * c + 3];
        ((float4*)outlc)[c] = v;
    }

    // stage relu(feats)*2^14 as f16 into per-wave LDS [64][40]
    f16* fbuf = wbuf[wave];
#pragma unroll
    for (int c = 0; c < 4; ++c) {
        f16x8 v;
#pragma unroll
        for (int j = 0; j < 8; ++j)
            v[j] = (f16)(fmaxf(fr[8 * c + j], 0.f) * 16384.f);
        *(f16x8*)&fbuf[lane * 40 + c * 8] = v;
    }

    __syncthreads();   // weights visible to all waves

    const int lr = lane & 15;
    const int lg = lane >> 4;
    f16* hbuf = wbuf[wave];

    // layer 0
    {
        f16x8 bf[4];
        float bia[4];
#pragma unroll
        for (int nt = 0; nt < 4; ++nt) {
            bf[nt] = *(const f16x8*)&w0s[(nt * 16 + lr) * 40 + lg * 8];
            bia[nt] = b0[nt * 16 + lr];
        }
#pragma unroll
        for (int mt = 3; mt >= 0; --mt) {
            f16x8 a = *(const f16x8*)&fbuf[(mt * 16 + lr) * 40 + lg * 8];
#pragma unroll
            for (int nt = 0; nt < 4; ++nt) {
                f32x4 c = {0.f, 0.f, 0.f, 0.f};
                c = __builtin_amdgcn_mfma_f32_16x16x32_f16(a, bf[nt], c, 0, 0, 0);
#pragma unroll
                for (int q = 0; q < 4; ++q) {
                    float h = fmaxf(c[q] * (1.0f / 16384.f) + bia[nt], 0.f);
                    hbuf[(mt * 16 + lg * 4 + q) * 72 + nt * 16 + lr] = (f16)h;
                }
            }
        }
    }

    // layer 1
    {
        f16x8 bf[4][2];
        float bia[4];
#pragma unroll
        for (int nt = 0; nt < 4; ++nt) {
            bf[nt][0] = *(const f16x8*)&w1s[(nt * 16 + lr) * 72 + lg * 8];
            bf[nt][1] = *(const f16x8*)&w1s[(nt * 16 + lr) * 72 + 32 + lg * 8];
            bia[nt] = b1[nt * 16 + lr];
        }
#pragma unroll
        for (int mt = 0; mt < 4; ++mt) {
            f16x8 a0 = *(const f16x8*)&hbuf[(mt * 16 + lr) * 72 + lg * 8];
            f16x8 a1 = *(const f16x8*)&hbuf[(mt * 16 + lr) * 72 + 32 + lg * 8];
#pragma unroll
            for (int nt = 0; nt < 4; ++nt) {
                f32x4 c = {0.f, 0.f, 0.f, 0.f};
                c = __builtin_amdgcn_mfma_f32_16x16x32_f16(a0, bf[nt][0], c, 0, 0, 0);
                c = __builtin_amdgcn_mfma_f32_16x16x32_f16(a1, bf[nt][1], c, 0, 0, 0);
#pragma unroll
                for (int q = 0; q < 4; ++q) {
                    float h = fmaxf(c[q] + bia[nt], 0.f);
                    hbuf[(mt * 16 + lg * 4 + q) * 72 + nt * 16 + lr] = (f16)h;
                }
            }
        }
    }

    // layer 2 -> h output at original positions
    {
        f16x8 bf0 = *(const f16x8*)&w2s[lr * 72 + lg * 8];
        f16x8 bf1 = *(const f16x8*)&w2s[lr * 72 + 32 + lg * 8];
        float bia2 = (lr < 3) ? b2[lr] : 0.f;
#pragma unroll
        for (int mt = 0; mt < 4; ++mt) {
            f16x8 a0 = *(const f16x8*)&hbuf[(mt * 16 + lr) * 72 + lg * 8];
            f16x8 a1 = *(const f16x8*)&hbuf[(mt * 16 + lr) * 72 + 32 + lg * 8];
            f32x4 c = {0.f, 0.f, 0.f, 0.f};
            c = __builtin_amdgcn_mfma_f32_16x16x32_f16(a0, bf0, c, 0, 0, 0);
            c = __builtin_amdgcn_mfma_f32_16x16x32_f16(a1, bf1, c, 0, 0, 0);
            if (lr < 3) {
#pragma unroll
                for (int q = 0; q < 4; ++q) {
                    int row = mt * 16 + lg * 4 + q;
                    int po = pidx ? (int)pidx[gblk + row] : (gblk + row);
                    out[(size_t)po * 3 + lr] = c[q] + bia2;
                }
            }
        }
    }
}

extern "C" void kernel_launch(void* const* d_in, const int* in_sizes, int n_in,
                              void* d_out, int out_size, void* d_ws, size_t ws_size,
                              hipStream_t stream) {
    const float* x    = (const float*)d_in[0];
    const float* cmax = (const float*)d_in[1];
    const float* emb  = (const float*)d_in[2];
    const float* w0   = (const float*)d_in[3];
    const float* b0   = (const float*)d_in[4];
    const float* w1   = (const float*)d_in[5];
    const float* b1   = (const float*)d_in[6];
    const float* w2   = (const float*)d_in[7];
    const float* b2   = (const float*)d_in[8];
    const int npts = in_sizes[0] / 2;
    const int nblk = npts / 256;

    LevelMeta meta;
    const double S = log2(2048.0 / 16.0) / 15.0;
    long long off = 0;
    for (int l = 0; l < NLEV; ++l) {
        double s = pow(2.0, l * S) * 16.0 - 1.0;
        int r = (int)ceil(s) + 1;
        long long pc = (long long)(r + 1) * (r + 1);
        if (pc > (1ll << 24)) pc = (1ll << 24);
        pc = ((pc + 7) / 8) * 8;
        meta.scale[l] = (float)s;
        meta.r1[l]    = r + 1;
        meta.off[l]   = (int)off;
        off += pc;
    }

    // ws: hist2d[NBIN*SRTBLK] u32 | binTot[NBIN] | binBase[NBIN] | pidx[npts] u32 | px[npts] f2
    size_t need = (size_t)NBIN * SRTBLK * 4 + (size_t)NBIN * 8 + (size_t)npts * 12;
    if (ws_size >= need && (npts % SRTBLK) == 0 && (npts & 255) == 0 && (nblk & 7) == 0) {
        unsigned* hist2d  = (unsigned*)d_ws;
        unsigned* binTot  = hist2d + (size_t)NBIN * SRTBLK;
        unsigned* binBase = binTot + NBIN;
        unsigned* pidx    = binBase + NBIN;
        float2*   px      = (float2*)(pidx + npts);
        const int ppb = npts / SRTBLK;

        hipLaunchKernelGGL(hist_kernel, dim3(SRTBLK), dim3(1024), 0, stream, x, cmax, hist2d, ppb);
        hipLaunchKernelGGL(scanbin_kernel, dim3(NBIN / 4), dim3(256), 0, stream, hist2d, binTot);
        hipLaunchKernelGGL(scantot_kernel, dim3(1), dim3(256), 0, stream, binTot, binBase);
        hipLaunchKernelGGL(scatter_kernel, dim3(SRTBLK), dim3(1024), 0, stream, x, cmax, hist2d, binBase, pidx, px, ppb);
        hipLaunchKernelGGL(hashmlp_kernel, dim3(nblk), dim3(256), 0, stream,
                           x, cmax, pidx, px, emb, w0, b0, w1, b1, w2, b2,
                           (float*)d_out, npts, nblk, meta);
    } else {
        hipLaunchKernelGGL(hashmlp_kernel, dim3(nblk), dim3(256), 0, stream,
                           x, cmax, (const unsigned*)nullptr, (const float2*)nullptr,
                           emb, w0, b0, w1, b1, w2, b2,
                           (float*)d_out, npts, nblk, meta);
    }
}

// Round 17
// 323.890 us; speedup vs baseline: 1.0281x; 1.0281x over previous
//
#include <hip/hip_runtime.h>
#include <math.h>

#define NLEV 16
#define RES  64
#define NBIN 4096     // 64x64 Morton bins
#define SRTBLK 256    // sort mega-blocks

typedef _Float16 f16;
typedef f16 f16x8 __attribute__((ext_vector_type(8)));
typedef float f32x4 __attribute__((ext_vector_type(4)));

struct LevelMeta {
    float scale[NLEV];
    int   r1[NLEV];    // grid row stride = r+1
    int   off[NLEV];   // element offset into embeddings table
};

struct alignas(8) F4 { float x, y, z, w; };

__device__ inline unsigned spread2d(unsigned v) {
    v = (v | (v << 4)) & 0x0F0Fu;
    v = (v | (v << 2)) & 0x3333u;
    v = (v | (v << 1)) & 0x5555u;
    return v;
}

__device__ inline unsigned bin_of(float x0, float x1) {
    int bx = (int)(x0 * (float)RES); bx = bx < 0 ? 0 : (bx > RES - 1 ? RES - 1 : bx);
    int by = (int)(x1 * (float)RES); by = by < 0 ? 0 : (by > RES - 1 ? RES - 1 : by);
    return spread2d((unsigned)bx) | (spread2d((unsigned)by) << 1);  // [0, NBIN)
}

// ---- K1: per-mega-block LDS histogram -> hist2d[bin][block] (no global atomics) ----
__global__ __launch_bounds__(1024)
void hist_kernel(const float* __restrict__ x, const float* __restrict__ cmax,
                 unsigned* __restrict__ hist2d, int ppb) {
    __shared__ unsigned lh[NBIN];
    const int t = threadIdx.x, bid = blockIdx.x;
    for (int i = t; i < NBIN; i += 1024) lh[i] = 0;
    __syncthreads();
    const float c0 = cmax[1], c1 = cmax[0];
    const int base = bid * ppb;
    for (int i = t; i < ppb; i += 1024) {
        float2 xy = ((const float2*)x)[base + i];
        atomicAdd(&lh[bin_of(xy.x / c0, xy.y / c1)], 1u);   // LDS atomic
    }
    __syncthreads();
    for (int i = t; i < NBIN; i += 1024)
        hist2d[i * SRTBLK + bid] = lh[i];                   // coalesced per wave
}

// ---- K2a: one wave per bin — in-place exclusive scan over blocks + bin total ----
__global__ __launch_bounds__(256)
void scanbin_kernel(unsigned* __restrict__ hist2d, unsigned* __restrict__ binTot) {
    const int wave = threadIdx.x >> 6, lane = threadIdx.x & 63;
    const int bin = blockIdx.x * 4 + wave;
    uint4* row = (uint4*)(hist2d + bin * SRTBLK);
    uint4 v = row[lane];
    unsigned s = v.x + v.y + v.z + v.w;
    unsigned xs = s;
#pragma unroll
    for (int o = 1; o < 64; o <<= 1) {
        unsigned y = (unsigned)__shfl_up((int)xs, o);
        if (lane >= o) xs += y;
    }
    unsigned ex = xs - s;   // exclusive base for this lane's 4 entries
    uint4 w;
    w.x = ex;
    w.y = w.x + v.x;
    w.z = w.y + v.y;
    w.w = w.z + v.z;
    row[lane] = w;          // hist2d becomes pre2d (in-bin exclusive prefix)
    if (lane == 63) binTot[bin] = xs;
}

// ---- K2b: exclusive scan of 4096 bin totals (one block, 16/thread) ----
__global__ __launch_bounds__(256)
void scantot_kernel(const unsigned* __restrict__ tot, unsigned* __restrict__ basev) {
    __shared__ unsigned wsum[4];
    int t = threadIdx.x;
    unsigned v[16];
    unsigned s = 0;
#pragma unroll
    for (int k = 0; k < 4; ++k) {
        uint4 h = ((const uint4*)tot)[t * 4 + k];
        v[4 * k] = h.x; v[4 * k + 1] = h.y; v[4 * k + 2] = h.z; v[4 * k + 3] = h.w;
        s += h.x + h.y + h.z + h.w;
    }
    int lane = t & 63, w = t >> 6;
    unsigned xs = s;
#pragma unroll
    for (int o = 1; o < 64; o <<= 1) {
        unsigned y = (unsigned)__shfl_up((int)xs, o);
        if (lane >= o) xs += y;
    }
    if (lane == 63) wsum[w] = xs;
    __syncthreads();
    unsigned wo = 0;
    for (int k = 0; k < w; ++k) wo += wsum[k];
    unsigned run = wo + xs - s;
#pragma unroll
    for (int j = 0; j < 16; ++j) {
        basev[t * 16 + j] = run;
        run += v[j];
    }
}

// ---- K3: scatter — rank = binBase[b] + pre2d[b][bid] + LDS-local seq ----
__global__ __launch_bounds__(1024)
void scatter_kernel(const float* __restrict__ x, const float* __restrict__ cmax,
                    const unsigned* __restrict__ pre2d,
                    const unsigned* __restrict__ binBase,
                    unsigned* __restrict__ pidx, float2* __restrict__ px, int ppb) {
    __shared__ unsigned lseq[NBIN];
    const int t = threadIdx.x, bid = blockIdx.x;
    for (int i = t; i < NBIN; i += 1024) lseq[i] = 0;
    __syncthreads();
    const float c0 = cmax[1], c1 = cmax[0];
    const int base = bid * ppb;
    for (int i = t; i < ppb; i += 1024) {
        int p = base + i;
        float2 xy = ((const float2*)x)[p];
        float x0 = xy.x / c0, x1 = xy.y / c1;
        unsigned b = bin_of(x0, x1);
        unsigned s = atomicAdd(&lseq[b], 1u);   // LDS atomic
        unsigned rank = binBase[b] + pre2d[b * SRTBLK + bid] + s;
        pidx[rank] = (unsigned)p;
        float2 v; v.x = x0; v.y = x1;
        px[rank] = v;
    }
}

// ---- fused hashgrid + MLP (proven body, LDS weights, 3 WG/CU) ----
// LDS: w0s 5120B + w1s 9216B + w2s 2304B + wbuf 36864B = 53504B -> 3 WG/CU
__global__ __launch_bounds__(256, 3)
void hashmlp_kernel(const float* __restrict__ x,
                    const float* __restrict__ cmax,
                    const unsigned* __restrict__ pidx,   // may be null (fallback)
                    const float2* __restrict__ px,       // may be null
                    const float* __restrict__ emb,
                    const float* __restrict__ w0,
                    const float* __restrict__ b0,
                    const float* __restrict__ w1,
                    const float* __restrict__ b1,
                    const float* __restrict__ w2,
                    const float* __restrict__ b2,
                    float* __restrict__ out,
                    int npts, int nblk,
                    LevelMeta meta)
{
    __shared__ f16 w0s[64 * 40];
    __shared__ f16 w1s[64 * 72];
    __shared__ f16 w2s[16 * 72];
    __shared__ f16 wbuf[4][4608];

    const int tid  = threadIdx.x;
    const int lane = tid & 63;
    const int wave = tid >> 6;

    // phase 1: weight loads into registers (stores deferred past gather)
    float w0t[8], w1t[16], w2t[4];
#pragma unroll
    for (int k = 0; k < 8; ++k)  w0t[k] = w0[tid + 256 * k];
#pragma unroll
    for (int k = 0; k < 16; ++k) w1t[k] = w1[tid + 256 * k];
#pragma unroll
    for (int k = 0; k < 4; ++k) {
        int i = tid + 256 * k; int r = i >> 6, c = i & 63;
        w2t[k] = (r < 3) ? w2[r * 64 + c] : 0.f;
    }

    // XCD-chunked swizzle: contiguous sorted (spatial) range per XCD
    int bid = blockIdx.x;
    int cpx = nblk >> 3;
    int swz = (bid & 7) * cpx + (bid >> 3);
    const int g = swz * 256 + tid;
    const int gblk = swz * 256 + wave * 64;

    int p;
    float x0, x1;
    if (pidx) {
        p = (int)pidx[g];
        float2 xy = px[g];
        x0 = xy.x; x1 = xy.y;
    } else {
        p = g;
        float2 xy = ((const float2*)x)[p];
        x0 = xy.x / cmax[1];
        x1 = xy.y / cmax[0];
    }

    // phase 2: gather (compiler-scheduled)
    float fr[32];
#pragma unroll
    for (int l = 0; l < NLEV; ++l) {
        const float sc = meta.scale[l];
        const int r1 = meta.r1[l];
        const int off = meta.off[l];
        float p0 = x0 * sc + 0.5f;
        float p1 = x1 * sc + 0.5f;
        float g0 = floorf(p0), g1 = floorf(p1);
        float f0 = p0 - g0, f1 = p1 - g1;
        int i0 = (int)g0, i1 = (int)g1;
        const float* ebf = emb + 2 * (off + i1 * r1 + i0);
        F4 lo = *(const F4*)ebf;              // e00.x e00.y e10.x e10.y
        F4 hi = *(const F4*)(ebf + 2 * r1);   // e01.x e01.y e11.x e11.y
        float omf0 = 1.f - f0, omf1 = 1.f - f1;
        float w00 = omf0 * omf1, w01 = omf0 * f1, w10 = f0 * omf1, w11 = f0 * f1;
        float a0 = w00 * lo.x; a0 += w01 * hi.x; a0 += w10 * lo.z; a0 += w11 * hi.z;
        float a1 = w00 * lo.y; a1 += w01 * hi.y; a1 += w10 * lo.w; a1 += w11 * hi.w;
        fr[2 * l]     = a0;
        fr[2 * l + 1] = a1;
    }

    // phase 3: weight stores to LDS
#pragma unroll
    for (int k = 0; k < 8; ++k)  { int i = tid + 256 * k; w0s[(i >> 5) * 40 + (i & 31)] = (f16)w0t[k]; }
#pragma unroll
    for (int k = 0; k < 16; ++k) { int i = tid + 256 * k; w1s[(i >> 6) * 72 + (i & 63)] = (f16)w1t[k]; }
#pragma unroll
    for (int k = 0; k < 4; ++k)  { int i = tid + 256 * k; w2s[(i >> 6) * 72 + (i & 63)] = (f16)w2t[k]; }

    // out_lc0 (fp32, exact) at original position
    float* outlc = out + (size_t)npts * 3 + (size_t)p * 32;
#pragma unroll
    for (int c = 0; c < 8; ++c) {
        float4 v;
        v.x = fr[4 * c]; v.y = fr[4 * c + 1]; v.z = fr[4 * c + 2]; v.w = fr[4 * c + 3];
        ((float4*)outlc)[c] = v;
    }

    // stage relu(feats)*2^14 as f16 into per-wave LDS [64][40]
    f16* fbuf = wbuf[wave];
#pragma unroll
    for (int c = 0; c < 4; ++c) {
        f16x8 v;
#pragma unroll
        for (int j = 0; j < 8; ++j)
            v[j] = (f16)(fmaxf(fr[8 * c + j], 0.f) * 16384.f);
        *(f16x8*)&fbuf[lane * 40 + c * 8] = v;
    }

    __syncthreads();   // weights visible to all waves

    const int lr = lane & 15;
    const int lg = lane >> 4;
    f16* hbuf = wbuf[wave];

    // layer 0
    {
        f16x8 bf[4];
        float bia[4];
#pragma unroll
        for (int nt = 0; nt < 4; ++nt) {
            bf[nt] = *(const f16x8*)&w0s[(nt * 16 + lr) * 40 + lg * 8];
            bia[nt] = b0[nt * 16 + lr];
        }
#pragma unroll
        for (int mt = 3; mt >= 0; --mt) {
            f16x8 a = *(const f16x8*)&fbuf[(mt * 16 + lr) * 40 + lg * 8];
#pragma unroll
            for (int nt = 0; nt < 4; ++nt) {
                f32x4 c = {0.f, 0.f, 0.f, 0.f};
                c = __builtin_amdgcn_mfma_f32_16x16x32_f16(a, bf[nt], c, 0, 0, 0);
#pragma unroll
                for (int q = 0; q < 4; ++q) {
                    float h = fmaxf(c[q] * (1.0f / 16384.f) + bia[nt], 0.f);
                    hbuf[(mt * 16 + lg * 4 + q) * 72 + nt * 16 + lr] = (f16)h;
                }
            }
        }
    }

    // layer 1
    {
        f16x8 bf[4][2];
        float bia[4];
#pragma unroll
        for (int nt = 0; nt < 4; ++nt) {
            bf[nt][0] = *(const f16x8*)&w1s[(nt * 16 + lr) * 72 + lg * 8];
            bf[nt][1] = *(const f16x8*)&w1s[(nt * 16 + lr) * 72 + 32 + lg * 8];
            bia[nt] = b1[nt * 16 + lr];
        }
#pragma unroll
        for (int mt = 0; mt < 4; ++mt) {
            f16x8 a0 = *(const f16x8*)&hbuf[(mt * 16 + lr) * 72 + lg * 8];
            f16x8 a1 = *(const f16x8*)&hbuf[(mt * 16 + lr) * 72 + 32 + lg * 8];
#pragma unroll
            for (int nt = 0; nt < 4; ++nt) {
                f32x4 c = {0.f, 0.f, 0.f, 0.f};
                c = __builtin_amdgcn_mfma_f32_16x16x32_f16(a0, bf[nt][0], c, 0, 0, 0);
                c = __builtin_amdgcn_mfma_f32_16x16x32_f16(a1, bf[nt][1], c, 0, 0, 0);
#pragma unroll
                for (int q = 0; q < 4; ++q) {
                    float h = fmaxf(c[q] + bia[nt], 0.f);
                    hbuf[(mt * 16 + lg * 4 + q) * 72 + nt * 16 + lr] = (f16)h;
                }
            }
        }
    }

    // layer 2 -> h output at original positions
    {
        f16x8 bf0 = *(const f16x8*)&w2s[lr * 72 + lg * 8];
        f16x8 bf1 = *(const f16x8*)&w2s[lr * 72 + 32 + lg * 8];
        float bia2 = (lr < 3) ? b2[lr] : 0.f;
#pragma unroll
        for (int mt = 0; mt < 4; ++mt) {
            f16x8 a0 = *(const f16x8*)&hbuf[(mt * 16 + lr) * 72 + lg * 8];
            f16x8 a1 = *(const f16x8*)&hbuf[(mt * 16 + lr) * 72 + 32 + lg * 8];
            f32x4 c = {0.f, 0.f, 0.f, 0.f};
            c = __builtin_amdgcn_mfma_f32_16x16x32_f16(a0, bf0, c, 0, 0, 0);
            c = __builtin_amdgcn_mfma_f32_16x16x32_f16(a1, bf1, c, 0, 0, 0);
            if (lr < 3) {
#pragma unroll
                for (int q = 0; q < 4; ++q) {
                    int row = mt * 16 + lg * 4 + q;
                    int po = pidx ? (int)pidx[gblk + row] : (gblk + row);
                    out[(size_t)po * 3 + lr] = c[q] + bia2;
                }
            }
        }
    }
}

extern "C" void kernel_launch(void* const* d_in, const int* in_sizes, int n_in,
                              void* d_out, int out_size, void* d_ws, size_t ws_size,
                              hipStream_t stream) {
    const float* x    = (const float*)d_in[0];
    const float* cmax = (const float*)d_in[1];
    const float* emb  = (const float*)d_in[2];
    const float* w0   = (const float*)d_in[3];
    const float* b0   = (const float*)d_in[4];
    const float* w1   = (const float*)d_in[5];
    const float* b1   = (const float*)d_in[6];
    const float* w2   = (const float*)d_in[7];
    const float* b2   = (const float*)d_in[8];
    const int npts = in_sizes[0] / 2;
    const int nblk = npts / 256;

    LevelMeta meta;
    const double S = log2(2048.0 / 16.0) / 15.0;
    long long off = 0;
    for (int l = 0; l < NLEV; ++l) {
        double s = pow(2.0, l * S) * 16.0 - 1.0;
        int r = (int)ceil(s) + 1;
        long long pc = (long long)(r + 1) * (r + 1);
        if (pc > (1ll << 24)) pc = (1ll << 24);
        pc = ((pc + 7) / 8) * 8;
        meta.scale[l] = (float)s;
        meta.r1[l]    = r + 1;
        meta.off[l]   = (int)off;
        off += pc;
    }

    // ws: hist2d[NBIN*SRTBLK] u32 | binTot[NBIN] | binBase[NBIN] | pidx[npts] u32 | px[npts] f2
    size_t need = (size_t)NBIN * SRTBLK * 4 + (size_t)NBIN * 8 + (size_t)npts * 12;
    if (ws_size >= need && (npts % SRTBLK) == 0 && (npts & 255) == 0 && (nblk & 7) == 0) {
        unsigned* hist2d  = (unsigned*)d_ws;
        unsigned* binTot  = hist2d + (size_t)NBIN * SRTBLK;
        unsigned* binBase = binTot + NBIN;
        unsigned* pidx    = binBase + NBIN;
        float2*   px      = (float2*)(pidx + npts);
        const int ppb = npts / SRTBLK;

        hipLaunchKernelGGL(hist_kernel, dim3(SRTBLK), dim3(1024), 0, stream, x, cmax, hist2d, ppb);
        hipLaunchKernelGGL(scanbin_kernel, dim3(NBIN / 4), dim3(256), 0, stream, hist2d, binTot);
        hipLaunchKernelGGL(scantot_kernel, dim3(1), dim3(256), 0, stream, binTot, binBase);
        hipLaunchKernelGGL(scatter_kernel, dim3(SRTBLK), dim3(1024), 0, stream, x, cmax, hist2d, binBase, pidx, px, ppb);
        hipLaunchKernelGGL(hashmlp_kernel, dim3(nblk), dim3(256), 0, stream,
                           x, cmax, pidx, px, emb, w0, b0, w1, b1, w2, b2,
                           (float*)d_out, npts, nblk, meta);
    } else {
        hipLaunchKernelGGL(hashmlp_kernel, dim3(nblk), dim3(256), 0, stream,
                           x, cmax, (const unsigned*)nullptr, (const float2*)nullptr,
                           emb, w0, b0, w1, b1, w2, b2,
                           (float*)d_out, npts, nblk, meta);
    }
}